// Round 1
// 85.891 us; speedup vs baseline: 1.0409x; 1.0409x over previous
//
#include <hip/hip_runtime.h>

// LatticeSnake: B=32, L=512, W=9.
// One block per group of G=8 consecutive windows of one batch. Consecutive
// window centers differ by <=2 (doubled coords), so the union of 8 windows
// fits in a <=23^3 box. Scatter all M=1023 snake points once into the actual
// bounding box in LDS, then emit all 8 windows' tiles as one flat
// float4-vectorized stream (block output base is 32B-aligned: i0 % 8 == 0).
//
// R1 change vs 87-us baseline: 512 threads/block (was 256). LDS (48.7 KB)
// caps residency at 3 blocks/CU either way, so 512t doubles waves/CU from
// 12 -> 24 for the same LDS footprint — this kernel is a chain of
// latency-bound phases (uniform idx preamble, zero, scatter w/ dependent
// global loads, decode+LDS-read+store) and was starved at 3 waves/SIMD.
// Also: odd-stride LDS padding (dyd|=1, dzd|=1) to break even-stride bank
// aliasing, float4 LDS zeroing, int4 center loads.

constexpr int L    = 512;
constexpr int W    = 9;
constexpr int W3   = W * W * W;          // 729
constexpr int HALF = W / 2;              // 4
constexpr int M    = 2 * L - 1;          // 1023 snake points
constexpr int G    = 8;                  // windows per block
constexpr int BOXW = 2 * (G - 1) + W;    // 23 (worst-case box width)
constexpr int BOXN = BOXW * BOXW * BOXW; // 12167 floats = 48.7 KB
constexpr int THREADS = 512;

typedef float vfloat4 __attribute__((ext_vector_type(4)));

__global__ __launch_bounds__(THREADS, 6) void lattice_snake_kernel(
    const float* __restrict__ acids,   // [B, L]
    const float* __restrict__ mask,    // [B, L]
    const int*   __restrict__ idx,     // [B, L, 3]
    float*       __restrict__ out)     // [B, L, 9,9,9,1]
{
    const int blk = blockIdx.x;
    const int b   = blk >> 6;          // / (L/G) = 64 groups per batch
    const int g   = blk & 63;
    const int i0  = g * G;
    const int tid = threadIdx.x;

    const int*   idxb = idx   + (size_t)b * L * 3;
    const float* ab   = acids + (size_t)b * L;
    const float* mb   = mask  + (size_t)b * L;

    // --- centers of the 8 windows (doubled coords) + actual bounding box ---
    // 24 contiguous ints starting at idxb + 3*i0; byte offset 12*i0 is a
    // multiple of 16 (i0 % 8 == 0), so int4 loads are aligned.
    int c[24];
    {
        const int4* cp = (const int4*)(idxb + 3 * i0);
#pragma unroll
        for (int q = 0; q < 6; ++q) {
            const int4 v = cp[q];
            c[4 * q + 0] = v.x; c[4 * q + 1] = v.y;
            c[4 * q + 2] = v.z; c[4 * q + 3] = v.w;
        }
    }
    int cxs[G], cys[G], czs[G];
    int mnx =  1 << 30, mny =  1 << 30, mnz =  1 << 30;
    int mxx = -(1 << 30), mxy = -(1 << 30), mxz = -(1 << 30);
#pragma unroll
    for (int w = 0; w < G; ++w) {
        const int cx = 2 * c[3 * w + 0] + 2 * (L - 1);
        const int cy = 2 * c[3 * w + 1] + 2 * (L - 1);
        const int cz = 2 * c[3 * w + 2] + 2 * (L - 1);
        cxs[w] = cx; cys[w] = cy; czs[w] = cz;
        mnx = min(mnx, cx); mxx = max(mxx, cx);
        mny = min(mny, cy); mxy = max(mxy, cy);
        mnz = min(mnz, cz); mxz = max(mxz, cz);
    }
    const int ox = mnx - HALF, oy = mny - HALF, oz = mnz - HALF;
    const int dxd = mxx - mnx + W;     // actual box dims, each <= 23
    int dyd = mxy - mny + W;
    int dzd = mxz - mnz + W;
    // Force odd y/z strides: all LDS access strides (dzd, dyd*dzd) become
    // odd -> no even-stride bank aliasing in the emit reads. The box is
    // scratch, so the extra (never-read) slots are harmless; padded dims
    // stay <= 23 so nbox <= BOXN.
    dyd |= 1;
    dzd |= 1;
    const int dydzd = dyd * dzd;
    const int nbox  = dxd * dydzd;

    __shared__ float box[BOXN + 9];    // +pad for float4 zero overrun
    __shared__ int   win_base[G];      // per-window base linear offset in box

    {
        const vfloat4 z = {0.0f, 0.0f, 0.0f, 0.0f};
        for (int k = tid * 4; k < nbox; k += THREADS * 4)
            *(vfloat4*)&box[k] = z;
    }
    if (tid == 0) {
#pragma unroll
        for (int w = 0; w < G; ++w) {
            const int bx = cxs[w] - HALF - ox;
            const int by = cys[w] - HALF - oy;
            const int bz = czs[w] - HALF - oz;
            win_base[w] = bx * dydzd + by * dzd + bz;
        }
    }
    __syncthreads();

    // --- scatter all snake points that land in the box ---
    for (int m = tid; m < M; m += THREADS) {
        int px, py, pz;
        float v;
        if (m < L) {
            px = 2 * idxb[3 * m + 0] + 2 * (L - 1);
            py = 2 * idxb[3 * m + 1] + 2 * (L - 1);
            pz = 2 * idxb[3 * m + 2] + 2 * (L - 1);
            v  = ab[m] * mb[m];
        } else {
            const int j = m - L;       // midpoint between residues j, j+1
            px = idxb[3 * j + 0] + idxb[3 * j + 3] + 2 * (L - 1);
            py = idxb[3 * j + 1] + idxb[3 * j + 4] + 2 * (L - 1);
            pz = idxb[3 * j + 2] + idxb[3 * j + 5] + 2 * (L - 1);
            v  = (ab[j] + ab[j + 1] + 1.0f) * mb[j + 1];
        }
        const int rx = px - ox, ry = py - oy, rz = pz - oz;
        if ((unsigned)rx < (unsigned)dxd && (unsigned)ry < (unsigned)dyd &&
            (unsigned)rz < (unsigned)dzd) {
            atomicAdd(&box[(rx * dyd + ry) * dzd + rz], v);
        }
    }
    __syncthreads();

    // --- emit: 8 windows = 5832 contiguous floats, float4 stores ---
    // Block base element index = (b*512 + i0)*729 with i0 % 8 == 0
    // -> multiple of 8 elements -> 32B aligned.
    float* ob = out + ((size_t)b * L + i0) * W3;
    for (int e = tid * 4; e < G * W3; e += THREADS * 4) {
        vfloat4 v4;
#pragma unroll
        for (int u = 0; u < 4; ++u) {
            const int ee = e + u;
            const int w  = ee / W3;          // window in group (magic-mul)
            const int k  = ee - w * W3;
            const int dx = k / 81;
            const int r  = k - dx * 81;
            const int dy = r / 9;
            const int dz = r - dy * 9;
            v4[u] = box[win_base[w] + dx * dydzd + dy * dzd + dz];
        }
        __builtin_nontemporal_store(v4, (vfloat4*)(ob + e));
    }
}

extern "C" void kernel_launch(void* const* d_in, const int* in_sizes, int n_in,
                              void* d_out, int out_size, void* d_ws, size_t ws_size,
                              hipStream_t stream) {
    const float* acids = (const float*)d_in[0];
    const float* mask  = (const float*)d_in[1];
    const int*   idx   = (const int*)d_in[2];
    float*       out   = (float*)d_out;

    const int B = in_sizes[0] / L;            // 32
    const int nblocks = B * (L / G);          // 2048 window groups

    lattice_snake_kernel<<<nblocks, THREADS, 0, stream>>>(acids, mask, idx, out);
}